// Round 5
// baseline (511.776 us; speedup 1.0000x reference)
//
#include <hip/hip_runtime.h>
#include <math.h>

#define HEADS 4
#define DIM 32
#define FDIM 128  // HEADS*DIM

typedef __attribute__((ext_vector_type(8))) short short8;
typedef __attribute__((ext_vector_type(16))) float float16;

__device__ __forceinline__ unsigned short f2bf(float x) {
  unsigned u = __float_as_uint(x);
  u += 0x7FFFu + ((u >> 16) & 1);   // round-to-nearest-even
  return (unsigned short)(u >> 16);
}
__device__ __forceinline__ float bf2f(unsigned short b) {
  return __uint_as_float(((unsigned)b) << 16);
}

// ---------------- input conversions (once per launch) ----------------
__global__ void convx_kernel(const float* __restrict__ x, unsigned short* __restrict__ xb,
                             int n4) {  // n4 = N*FDIM/4
  int i = blockIdx.x * 256 + threadIdx.x;
  if (i >= n4) return;
  float4 v = ((const float4*)x)[i];
  ushort4 o;
  o.x = f2bf(v.x); o.y = f2bf(v.y); o.z = f2bf(v.z); o.w = f2bf(v.w);
  ((ushort4*)xb)[i] = o;
}

// WT[(layer*R + r)][n][k] = bf16(W[layer][r][k][n])
__global__ void convw_kernel(const float* __restrict__ W1, const float* __restrict__ W2,
                             unsigned short* __restrict__ WT, int R) {
  int idx = blockIdx.x * 256 + threadIdx.x;
  if (idx >= 2 * R * FDIM * FDIM) return;
  int lr = idx >> 14;            // layer*R + r
  int rem = idx & 16383;
  int n = rem >> 7, k = rem & 127;
  const float* W = (lr < R) ? (W1 + (size_t)lr * FDIM * FDIM)
                            : (W2 + (size_t)(lr - R) * FDIM * FDIM);
  WT[idx] = f2bf(W[k * FDIM + n]);
}

// ---------------- adjacency: 2 interleaved linked sublists per (r,node) ----------
// head2[(r*N+d)*2 + (e&1)]; nxt2[r*E+e] = {next_edge, src}
__global__ void link_kernel(const int* __restrict__ edges, int* __restrict__ head2,
                            int2* __restrict__ nxt2, int E, int N, int R) {
  int i = blockIdx.x * blockDim.x + threadIdx.x;
  if (i >= R * E) return;
  int r = i / E, e = i - r * E;
  const int* ed = edges + (size_t)r * 2 * E;
  int s = ed[e], d = ed[E + e];
  int old = atomicExch(&head2[(r * N + d) * 2 + (e & 1)], e);
  nxt2[i] = make_int2(old, s);
}

// ---------------- LDS-free MFMA matmul: feat[r] = A @ W[r]^T' (bf16 in/out) -------
__global__ __launch_bounds__(256) void mm_kernel(const unsigned short* __restrict__ Ab,
    const unsigned short* __restrict__ WTl, unsigned short* __restrict__ featb_all, int N) {
  int r = blockIdx.y;
  const unsigned short* WT = WTl + (size_t)r * FDIM * FDIM;
  int row0 = blockIdx.x * 64;
  int t = threadIdx.x, lane = t & 63, w = t >> 6;
  int m = lane & 31, q = lane >> 5;
  int m0 = (w & 1) * 32;          // row half
  int n0 = (w >> 1) * 64;         // col half (2 tiles of 32)
  int arow = row0 + m0 + m;
  bool valid = arow < N;
  const unsigned short* ap = Ab + (size_t)arow * FDIM;
  const unsigned short* bp0 = WT + (size_t)(n0 + m) * FDIM;
  const unsigned short* bp1 = WT + (size_t)(n0 + 32 + m) * FDIM;
  float16 acc0 = 0.f, acc1 = 0.f;
#pragma unroll
  for (int kc = 0; kc < 8; ++kc) {
    int ko = kc * 16 + q * 8;
    short8 a = valid ? *(const short8*)(ap + ko) : (short8)(short)0;
    short8 b0 = *(const short8*)(bp0 + ko);
    short8 b1 = *(const short8*)(bp1 + ko);
    acc0 = __builtin_amdgcn_mfma_f32_32x32x16_bf16(a, b0, acc0, 0, 0, 0);
    acc1 = __builtin_amdgcn_mfma_f32_32x32x16_bf16(a, b1, acc1, 0, 0, 0);
  }
  unsigned short* fb = featb_all + (size_t)r * N * FDIM;
#pragma unroll
  for (int tile = 0; tile < 2; ++tile) {
    float16 acc = (tile == 0) ? acc0 : acc1;
    int c = n0 + tile * 32 + m;
#pragma unroll
    for (int reg = 0; reg < 16; ++reg) {
      int rr = (reg & 3) + 8 * (reg >> 2) + 4 * q;   // C-layout (m74/m101)
      int gr = row0 + m0 + rr;
      if (gr < N) fb[(size_t)gr * FDIM + c] = f2bf(acc[reg]);
    }
  }
}

// ---------------- attention coefficients from bf16 feat ----------------
__global__ void coef_kernel(const unsigned short* __restrict__ featb,
                            const float* __restrict__ al_all, const float* __restrict__ ar_all,
                            float* __restrict__ el, float* __restrict__ er, int N) {
  int r = blockIdx.y;
  int idx = blockIdx.x * 256 + threadIdx.x;
  if (idx >= N * HEADS) return;
  int node = idx >> 2, hd = idx & 3;
  const uint4* fp = (const uint4*)(featb + (size_t)r * N * FDIM + (size_t)node * FDIM + hd * DIM);
  const float4* a4 = (const float4*)(al_all + r * FDIM + hd * DIM);
  const float4* b4 = (const float4*)(ar_all + r * FDIM + hd * DIM);
  uint4 u[4] = {fp[0], fp[1], fp[2], fp[3]};
  unsigned uu[16] = {u[0].x, u[0].y, u[0].z, u[0].w, u[1].x, u[1].y, u[1].z, u[1].w,
                     u[2].x, u[2].y, u[2].z, u[2].w, u[3].x, u[3].y, u[3].z, u[3].w};
  float sl = 0.f, sr = 0.f;
#pragma unroll
  for (int g = 0; g < 8; ++g) {
    float4 av = a4[g], bv = b4[g];
    float f0 = bf2f((unsigned short)(uu[2 * g] & 0xFFFF));
    float f1 = bf2f((unsigned short)(uu[2 * g] >> 16));
    float f2 = bf2f((unsigned short)(uu[2 * g + 1] & 0xFFFF));
    float f3 = bf2f((unsigned short)(uu[2 * g + 1] >> 16));
    sl += f0 * av.x + f1 * av.y + f2 * av.z + f3 * av.w;
    sr += f0 * bv.x + f1 * bv.y + f2 * bv.z + f3 * bv.w;
  }
  el[(size_t)r * N * 4 + idx] = sl;
  er[(size_t)r * N * 4 + idx] = sr;
}

// ---------------- layer-1 aggregation: (node, head, sublist) per thread, r = grid.y
// octet = 4 heads x 2 sublists of one node; sublist partials merged via shfl_xor(4).
__global__ __launch_bounds__(256) void agg1_kernel(const unsigned short* __restrict__ featb,
    const float* __restrict__ el, const float* __restrict__ er,
    const int* __restrict__ head2, const int2* __restrict__ nxt2,
    const float* __restrict__ bias, float* __restrict__ h0, float* __restrict__ h1,
    int N, int E) {
  int r = blockIdx.y;
  int t = blockIdx.x * 256 + threadIdx.x;
  int node = t >> 3;
  if (node >= N) return;
  int hd = t & 3, sub = (t >> 2) & 1;
  const unsigned short* f = featb + (size_t)r * N * FDIM + hd * DIM;
  const float* elr = el + (size_t)r * N * 4;
  const int2* nx = nxt2 + (size_t)r * E;
  float er_h = er[(size_t)r * N * 4 + node * 4 + hd];
  float l = 0.f, a[32];
#pragma unroll
  for (int i = 0; i < 32; ++i) a[i] = 0.f;
  int e = head2[(r * N + node) * 2 + sub];
  while (e >= 0) {
    int2 pr = nx[e];                       // {next, src} one line
    int s = pr.y;
    float ee = elr[s * 4 + hd] + er_h;
    ee = ee > 0.f ? ee : 0.2f * ee;        // LeakyReLU
    float p = __expf(ee);                  // no max-sub: |e| small, fp32 safe
    const uint4* fp = (const uint4*)(f + (size_t)s * FDIM);
    uint4 u0 = fp[0], u1 = fp[1], u2 = fp[2], u3 = fp[3];
    l += p;
    unsigned uu[16] = {u0.x, u0.y, u0.z, u0.w, u1.x, u1.y, u1.z, u1.w,
                       u2.x, u2.y, u2.z, u2.w, u3.x, u3.y, u3.z, u3.w};
#pragma unroll
    for (int j = 0; j < 16; ++j) {
      float f0 = __uint_as_float(uu[j] << 16);
      float f1 = __uint_as_float(uu[j] & 0xFFFF0000u);
      a[2 * j]     = fmaf(p, f0, a[2 * j]);
      a[2 * j + 1] = fmaf(p, f1, a[2 * j + 1]);
    }
    e = pr.x;
  }
  // merge the two sublists
  l += __shfl_xor(l, 4);
#pragma unroll
  for (int i = 0; i < 32; ++i) a[i] += __shfl_xor(a[i], 4);
  if (sub == 0) {
    float inv = (l > 0.f) ? 1.f / l : 0.f;
    float* hr = (r == 0) ? h0 : h1;
    const float4* b4 = (const float4*)(bias + r * FDIM + hd * DIM);
    float4* hp = (float4*)(hr + (size_t)node * FDIM + hd * DIM);
#pragma unroll
    for (int g = 0; g < 8; ++g) {
      float4 bv = b4[g];
      float v0 = a[4 * g] * inv + bv.x;
      float v1 = a[4 * g + 1] * inv + bv.y;
      float v2 = a[4 * g + 2] * inv + bv.z;
      float v3 = a[4 * g + 3] * inv + bv.w;
      v0 = v0 > 0.f ? v0 : __expf(v0) - 1.f;   // ELU
      v1 = v1 > 0.f ? v1 : __expf(v1) - 1.f;
      v2 = v2 > 0.f ? v2 : __expf(v2) - 1.f;
      v3 = v3 > 0.f ? v3 : __expf(v3) - 1.f;
      hp[g] = make_float4(v0, v1, v2, v3);
    }
  }
}

// ---------------- combine: hf = h0+h1 (in-place into h0), hb = bf16(hf) -----------
__global__ void combine_kernel(float* __restrict__ h0, const float* __restrict__ h1,
                               unsigned short* __restrict__ hb, int n4) {
  int i = blockIdx.x * 256 + threadIdx.x;
  if (i >= n4) return;
  float4 v0 = ((const float4*)h0)[i];
  float4 v1 = ((const float4*)h1)[i];
  float4 s = make_float4(v0.x + v1.x, v0.y + v1.y, v0.z + v1.z, v0.w + v1.w);
  ((float4*)h0)[i] = s;
  ushort4 o;
  o.x = f2bf(s.x); o.y = f2bf(s.y); o.z = f2bf(s.z); o.w = f2bf(s.w);
  ((ushort4*)hb)[i] = o;
}

// ---------------- layer-2 aggregation + residual + bias + head-mean ----------------
__global__ __launch_bounds__(256) void agg2_kernel(const unsigned short* __restrict__ featb,
    const float* __restrict__ el, const float* __restrict__ er,
    const int* __restrict__ head2, const int2* __restrict__ nxt2,
    const float* __restrict__ bias, const float* __restrict__ hf,
    float* __restrict__ out, int N, int E) {
  int r = blockIdx.y;
  int t = blockIdx.x * 256 + threadIdx.x;
  int node = t >> 3;
  if (node >= N) return;
  int hd = t & 3, sub = (t >> 2) & 1;
  const unsigned short* f = featb + (size_t)r * N * FDIM + hd * DIM;
  const float* elr = el + (size_t)r * N * 4;
  const int2* nx = nxt2 + (size_t)r * E;
  float er_h = er[(size_t)r * N * 4 + node * 4 + hd];
  float l = 0.f, a[32];
#pragma unroll
  for (int i = 0; i < 32; ++i) a[i] = 0.f;
  int e = head2[(r * N + node) * 2 + sub];
  while (e >= 0) {
    int2 pr = nx[e];
    int s = pr.y;
    float ee = elr[s * 4 + hd] + er_h;
    ee = ee > 0.f ? ee : 0.2f * ee;
    float p = __expf(ee);
    const uint4* fp = (const uint4*)(f + (size_t)s * FDIM);
    uint4 u0 = fp[0], u1 = fp[1], u2 = fp[2], u3 = fp[3];
    l += p;
    unsigned uu[16] = {u0.x, u0.y, u0.z, u0.w, u1.x, u1.y, u1.z, u1.w,
                       u2.x, u2.y, u2.z, u2.w, u3.x, u3.y, u3.z, u3.w};
#pragma unroll
    for (int j = 0; j < 16; ++j) {
      float f0 = __uint_as_float(uu[j] << 16);
      float f1 = __uint_as_float(uu[j] & 0xFFFF0000u);
      a[2 * j]     = fmaf(p, f0, a[2 * j]);
      a[2 * j + 1] = fmaf(p, f1, a[2 * j + 1]);
    }
    e = pr.x;
  }
  l += __shfl_xor(l, 4);
#pragma unroll
  for (int i = 0; i < 32; ++i) a[i] += __shfl_xor(a[i], 4);
  float inv = (l > 0.f) ? 1.f / l : 0.f;
  const float4* b4 = (const float4*)(bias + r * FDIM + hd * DIM);
  const float4* rv4 = (const float4*)(hf + (size_t)node * FDIM + hd * DIM);
  float vals[32];
#pragma unroll
  for (int g = 0; g < 8; ++g) {
    float4 bv = b4[g], rv = rv4[g];
    vals[4 * g]     = a[4 * g] * inv + rv.x + bv.x;
    vals[4 * g + 1] = a[4 * g + 1] * inv + rv.y + bv.y;
    vals[4 * g + 2] = a[4 * g + 2] * inv + rv.z + bv.z;
    vals[4 * g + 3] = a[4 * g + 3] * inv + rv.w + bv.w;
  }
  // sum over the 4 head lanes (butterfly -> all lanes hold totals)
#pragma unroll
  for (int i = 0; i < 32; ++i) {
    float v = vals[i];
    v += __shfl_xor(v, 1);
    v += __shfl_xor(v, 2);
    vals[i] = v;
  }
  if (sub == 0) {   // lane hd writes its 8-dim slice; R=2 -> a+b exact & deterministic
    float* op = out + (size_t)node * 32 + hd * 8;
#pragma unroll
    for (int j = 0; j < 8; ++j)
      atomicAdd(op + j, 0.25f * vals[hd * 8 + j]);
  }
}

extern "C" void kernel_launch(void* const* d_in, const int* in_sizes, int n_in,
                              void* d_out, int out_size, void* d_ws, size_t ws_size,
                              hipStream_t stream) {
  const float* x   = (const float*)d_in[0];
  const float* W1  = (const float*)d_in[1];
  const float* al1 = (const float*)d_in[2];
  const float* ar1 = (const float*)d_in[3];
  const float* b1  = (const float*)d_in[4];
  const float* W2  = (const float*)d_in[5];
  const float* al2 = (const float*)d_in[6];
  const float* ar2 = (const float*)d_in[7];
  const float* b2  = (const float*)d_in[8];
  const int* edges = (const int*)d_in[9];
  float* out = (float*)d_out;

  const int N = in_sizes[0] / FDIM;          // 50000
  const int R = in_sizes[1] / (FDIM * FDIM); // 2
  const int E = in_sizes[9] / (2 * R);       // 800000

  char* ws = (char*)d_ws;
  size_t off = 0;
  auto alloc = [&](size_t bytes) {
    char* p = ws + off;
    off += (bytes + 255) & ~(size_t)255;
    return p;
  };
  unsigned short* featb = (unsigned short*)alloc((size_t)R * N * FDIM * 2);  // 25.6 MB
  unsigned short* xb    = (unsigned short*)alloc((size_t)N * FDIM * 2);      // 12.8 MB (reused as hb)
  unsigned short* WT    = (unsigned short*)alloc((size_t)2 * R * FDIM * FDIM * 2);
  float* el = (float*)alloc((size_t)R * N * 4 * 4);
  float* er = (float*)alloc((size_t)R * N * 4 * 4);
  float* h0 = (float*)alloc((size_t)N * FDIM * 4);   // becomes hf (in-place combine)
  float* h1 = (float*)alloc((size_t)N * FDIM * 4);
  int* head2 = (int*)alloc((size_t)R * N * 2 * 4);
  int2* nxt2 = (int2*)alloc((size_t)R * E * 8);
  unsigned short* hb = xb;  // xb dead after layer-1 mm
  float* hf = h0;

  hipMemsetAsync(head2, 0xFF, (size_t)R * N * 2 * 4, stream);
  hipMemsetAsync(out, 0, (size_t)N * 32 * 4, stream);

  int n4 = N * FDIM / 4;
  convx_kernel<<<(n4 + 255) / 256, 256, 0, stream>>>(x, xb, n4);
  convw_kernel<<<(2 * R * FDIM * FDIM + 255) / 256, 256, 0, stream>>>(W1, W2, WT, R);
  link_kernel<<<(R * E + 255) / 256, 256, 0, stream>>>(edges, head2, nxt2, E, N, R);

  dim3 mmgrid((N + 63) / 64, R);
  dim3 cgrid((N * HEADS + 255) / 256, R);
  dim3 agrid((N * 8 + 255) / 256, R);

  // ---- layer 1 ----
  mm_kernel<<<mmgrid, 256, 0, stream>>>(xb, WT, featb, N);
  coef_kernel<<<cgrid, 256, 0, stream>>>(featb, al1, ar1, el, er, N);
  agg1_kernel<<<agrid, 256, 0, stream>>>(featb, el, er, head2, nxt2, b1, h0, h1, N, E);
  combine_kernel<<<(n4 + 255) / 256, 256, 0, stream>>>(h0, h1, hb, n4);

  // ---- layer 2 ----
  mm_kernel<<<mmgrid, 256, 0, stream>>>(hb, WT + (size_t)R * FDIM * FDIM, featb, N);
  coef_kernel<<<cgrid, 256, 0, stream>>>(featb, al2, ar2, el, er, N);
  agg2_kernel<<<agrid, 256, 0, stream>>>(featb, el, er, head2, nxt2, b2, hf, out, N, E);
}

// Round 6
// 470.123 us; speedup vs baseline: 1.0886x; 1.0886x over previous
//
#include <hip/hip_runtime.h>
#include <math.h>

#define HEADS 4
#define DIM 32
#define FDIM 128  // HEADS*DIM

typedef __attribute__((ext_vector_type(8))) short short8;
typedef __attribute__((ext_vector_type(16))) float float16;

__device__ __forceinline__ unsigned short f2bf(float x) {
  unsigned u = __float_as_uint(x);
  u += 0x7FFFu + ((u >> 16) & 1);   // round-to-nearest-even
  return (unsigned short)(u >> 16);
}
__device__ __forceinline__ float bf2f(unsigned short b) {
  return __uint_as_float(((unsigned)b) << 16);
}

// ---------------- prep: W->bf16 transposed  +  linked-list adjacency ----------------
// WT[(layer*R+r)][n][k] = bf16(W[layer][r][k][n])
// head2[(r*N+d)*2 + (e&1)] chain heads; nxt2[r*E+e] = {next_edge, src}
__global__ void prep_kernel(const float* __restrict__ W1, const float* __restrict__ W2,
                            unsigned short* __restrict__ WT,
                            const int* __restrict__ edges, int* __restrict__ head2,
                            int2* __restrict__ nxt2, int E, int N, int R) {
  int idx = blockIdx.x * 256 + threadIdx.x;
  int NW = 2 * R * FDIM * FDIM;
  if (idx < NW) {
    int lr = idx >> 14;
    int rem = idx & 16383;
    int n = rem >> 7, k = rem & 127;
    const float* W = (lr < R) ? (W1 + (size_t)lr * FDIM * FDIM)
                              : (W2 + (size_t)(lr - R) * FDIM * FDIM);
    WT[idx] = f2bf(W[k * FDIM + n]);
    return;
  }
  int i = idx - NW;
  if (i >= R * E) return;
  int r = i / E, e = i - r * E;
  const int* ed = edges + (size_t)r * 2 * E;
  int s = ed[e], d = ed[E + e];
  int old = atomicExch(&head2[(r * N + d) * 2 + (e & 1)], e);
  nxt2[i] = make_int2(old, s);
}

// ---------------- LDS-free MFMA matmul: feat[r] = bf16(A_fp32) @ WT[r] ----------------
__global__ __launch_bounds__(256) void mm_kernel(const float* __restrict__ A,
    const unsigned short* __restrict__ WTl, unsigned short* __restrict__ featb_all, int N) {
  int r = blockIdx.y;
  const unsigned short* WT = WTl + (size_t)r * FDIM * FDIM;
  int row0 = blockIdx.x * 64;
  int t = threadIdx.x, lane = t & 63, w = t >> 6;
  int m = lane & 31, q = lane >> 5;
  int m0 = (w & 1) * 32;          // row half
  int n0 = (w >> 1) * 64;         // col half (2 tiles of 32)
  int arow = row0 + m0 + m;
  bool valid = arow < N;
  const float* ap = A + (size_t)arow * FDIM;
  const unsigned short* bp0 = WT + (size_t)(n0 + m) * FDIM;
  const unsigned short* bp1 = WT + (size_t)(n0 + 32 + m) * FDIM;
  float16 acc0 = 0.f, acc1 = 0.f;
#pragma unroll
  for (int kc = 0; kc < 8; ++kc) {
    int ko = kc * 16 + q * 8;
    short8 a = (short8)(short)0;
    if (valid) {
      float4 v0 = *(const float4*)(ap + ko);
      float4 v1 = *(const float4*)(ap + ko + 4);
      a[0] = (short)f2bf(v0.x); a[1] = (short)f2bf(v0.y);
      a[2] = (short)f2bf(v0.z); a[3] = (short)f2bf(v0.w);
      a[4] = (short)f2bf(v1.x); a[5] = (short)f2bf(v1.y);
      a[6] = (short)f2bf(v1.z); a[7] = (short)f2bf(v1.w);
    }
    short8 b0 = *(const short8*)(bp0 + ko);
    short8 b1 = *(const short8*)(bp1 + ko);
    acc0 = __builtin_amdgcn_mfma_f32_32x32x16_bf16(a, b0, acc0, 0, 0, 0);
    acc1 = __builtin_amdgcn_mfma_f32_32x32x16_bf16(a, b1, acc1, 0, 0, 0);
  }
  unsigned short* fb = featb_all + (size_t)r * N * FDIM;
#pragma unroll
  for (int tile = 0; tile < 2; ++tile) {
    float16 acc = (tile == 0) ? acc0 : acc1;
    int c = n0 + tile * 32 + m;
#pragma unroll
    for (int reg = 0; reg < 16; ++reg) {
      int rr = (reg & 3) + 8 * (reg >> 2) + 4 * q;   // C-layout (m74/m101)
      int gr = row0 + m0 + rr;
      if (gr < N) fb[(size_t)gr * FDIM + c] = f2bf(acc[reg]);
    }
  }
}

// ---------------- attention coefficients from bf16 feat ----------------
__global__ void coef_kernel(const unsigned short* __restrict__ featb,
                            const float* __restrict__ al_all, const float* __restrict__ ar_all,
                            float* __restrict__ el, float* __restrict__ er, int N) {
  int r = blockIdx.y;
  int idx = blockIdx.x * 256 + threadIdx.x;
  if (idx >= N * HEADS) return;
  int node = idx >> 2, hd = idx & 3;
  const uint4* fp = (const uint4*)(featb + (size_t)r * N * FDIM + (size_t)node * FDIM + hd * DIM);
  const float4* a4 = (const float4*)(al_all + r * FDIM + hd * DIM);
  const float4* b4 = (const float4*)(ar_all + r * FDIM + hd * DIM);
  uint4 u[4] = {fp[0], fp[1], fp[2], fp[3]};
  unsigned uu[16] = {u[0].x, u[0].y, u[0].z, u[0].w, u[1].x, u[1].y, u[1].z, u[1].w,
                     u[2].x, u[2].y, u[2].z, u[2].w, u[3].x, u[3].y, u[3].z, u[3].w};
  float sl = 0.f, sr = 0.f;
#pragma unroll
  for (int g = 0; g < 8; ++g) {
    float4 av = a4[g], bv = b4[g];
    float f0 = bf2f((unsigned short)(uu[2 * g] & 0xFFFF));
    float f1 = bf2f((unsigned short)(uu[2 * g] >> 16));
    float f2 = bf2f((unsigned short)(uu[2 * g + 1] & 0xFFFF));
    float f3 = bf2f((unsigned short)(uu[2 * g + 1] >> 16));
    sl += f0 * av.x + f1 * av.y + f2 * av.z + f3 * av.w;
    sr += f0 * bv.x + f1 * bv.y + f2 * bv.z + f3 * bv.w;
  }
  el[(size_t)r * N * 4 + idx] = sl;
  er[(size_t)r * N * 4 + idx] = sr;
}

// ---------------- layer-1 aggregation ----------------
// 8 threads/node: 4 heads x 2 sublists. Serial over relations; sublists merged via
// shfl_xor(4). No max-subtraction (pre-activations tame, validated R4/R5).
__global__ __launch_bounds__(256) void agg1_kernel(const unsigned short* __restrict__ featb,
    const float* __restrict__ el, const float* __restrict__ er,
    const int* __restrict__ head2, const int2* __restrict__ nxt2,
    const float* __restrict__ bias, float* __restrict__ hout, int N, int E, int R) {
  int t = blockIdx.x * 256 + threadIdx.x;
  int node = t >> 3;
  if (node >= N) return;
  int hd = t & 3, sub = (t >> 2) & 1;
  float tot[32];
#pragma unroll
  for (int i = 0; i < 32; ++i) tot[i] = 0.f;
  for (int r = 0; r < R; ++r) {
    const unsigned short* f = featb + (size_t)r * N * FDIM + hd * DIM;
    const float* elr = el + (size_t)r * N * 4;
    const int2* nx = nxt2 + (size_t)r * E;
    float er_h = er[(size_t)r * N * 4 + node * 4 + hd];
    float l = 0.f, a[32];
#pragma unroll
    for (int i = 0; i < 32; ++i) a[i] = 0.f;
    int e = head2[(r * N + node) * 2 + sub];
    while (e >= 0) {
      int2 pr = nx[e];                       // {next, src}: one scattered line
      int s = pr.y;
      float ee = elr[s * 4 + hd] + er_h;
      ee = ee > 0.f ? ee : 0.2f * ee;        // LeakyReLU
      float p = __expf(ee);
      const uint4* fp = (const uint4*)(f + (size_t)s * FDIM);
      uint4 u0 = fp[0], u1 = fp[1], u2 = fp[2], u3 = fp[3];
      l += p;
      unsigned uu[16] = {u0.x, u0.y, u0.z, u0.w, u1.x, u1.y, u1.z, u1.w,
                         u2.x, u2.y, u2.z, u2.w, u3.x, u3.y, u3.z, u3.w};
#pragma unroll
      for (int j = 0; j < 16; ++j) {
        float f0 = __uint_as_float(uu[j] << 16);
        float f1 = __uint_as_float(uu[j] & 0xFFFF0000u);
        a[2 * j]     = fmaf(p, f0, a[2 * j]);
        a[2 * j + 1] = fmaf(p, f1, a[2 * j + 1]);
      }
      e = pr.x;
    }
    l += __shfl_xor(l, 4);                   // merge sublists
#pragma unroll
    for (int i = 0; i < 32; ++i) a[i] += __shfl_xor(a[i], 4);
    float inv = (l > 0.f) ? 1.f / l : 0.f;
    const float4* b4 = (const float4*)(bias + r * FDIM + hd * DIM);
#pragma unroll
    for (int g = 0; g < 8; ++g) {
      float4 bv = b4[g];
      float v0 = a[4 * g] * inv + bv.x;
      float v1 = a[4 * g + 1] * inv + bv.y;
      float v2 = a[4 * g + 2] * inv + bv.z;
      float v3 = a[4 * g + 3] * inv + bv.w;
      tot[4 * g]     += v0 > 0.f ? v0 : __expf(v0) - 1.f;   // ELU
      tot[4 * g + 1] += v1 > 0.f ? v1 : __expf(v1) - 1.f;
      tot[4 * g + 2] += v2 > 0.f ? v2 : __expf(v2) - 1.f;
      tot[4 * g + 3] += v3 > 0.f ? v3 : __expf(v3) - 1.f;
    }
  }
  if (sub == 0) {
    float4* hp = (float4*)(hout + (size_t)node * FDIM + hd * DIM);
#pragma unroll
    for (int g = 0; g < 8; ++g)
      hp[g] = make_float4(tot[4 * g], tot[4 * g + 1], tot[4 * g + 2], tot[4 * g + 3]);
  }
}

// ---------------- layer-2 aggregation + residual + bias + head-mean ----------------
__global__ __launch_bounds__(256) void agg2_kernel(const unsigned short* __restrict__ featb,
    const float* __restrict__ el, const float* __restrict__ er,
    const int* __restrict__ head2, const int2* __restrict__ nxt2,
    const float* __restrict__ bias, const float* __restrict__ hf,
    float* __restrict__ out, int N, int E, int R) {
  int t = blockIdx.x * 256 + threadIdx.x;
  int node = t >> 3;
  if (node >= N) return;
  int hd = t & 3, sub = (t >> 2) & 1;
  float tot[32];
#pragma unroll
  for (int i = 0; i < 32; ++i) tot[i] = 0.f;
  for (int r = 0; r < R; ++r) {
    const unsigned short* f = featb + (size_t)r * N * FDIM + hd * DIM;
    const float* elr = el + (size_t)r * N * 4;
    const int2* nx = nxt2 + (size_t)r * E;
    float er_h = er[(size_t)r * N * 4 + node * 4 + hd];
    float l = 0.f, a[32];
#pragma unroll
    for (int i = 0; i < 32; ++i) a[i] = 0.f;
    int e = head2[(r * N + node) * 2 + sub];
    while (e >= 0) {
      int2 pr = nx[e];
      int s = pr.y;
      float ee = elr[s * 4 + hd] + er_h;
      ee = ee > 0.f ? ee : 0.2f * ee;
      float p = __expf(ee);
      const uint4* fp = (const uint4*)(f + (size_t)s * FDIM);
      uint4 u0 = fp[0], u1 = fp[1], u2 = fp[2], u3 = fp[3];
      l += p;
      unsigned uu[16] = {u0.x, u0.y, u0.z, u0.w, u1.x, u1.y, u1.z, u1.w,
                         u2.x, u2.y, u2.z, u2.w, u3.x, u3.y, u3.z, u3.w};
#pragma unroll
      for (int j = 0; j < 16; ++j) {
        float f0 = __uint_as_float(uu[j] << 16);
        float f1 = __uint_as_float(uu[j] & 0xFFFF0000u);
        a[2 * j]     = fmaf(p, f0, a[2 * j]);
        a[2 * j + 1] = fmaf(p, f1, a[2 * j + 1]);
      }
      e = pr.x;
    }
    l += __shfl_xor(l, 4);
#pragma unroll
    for (int i = 0; i < 32; ++i) a[i] += __shfl_xor(a[i], 4);
    float inv = (l > 0.f) ? 1.f / l : 0.f;
    const float4* b4 = (const float4*)(bias + r * FDIM + hd * DIM);
#pragma unroll
    for (int g = 0; g < 8; ++g) {
      float4 bv = b4[g];
      tot[4 * g]     += a[4 * g] * inv + bv.x;
      tot[4 * g + 1] += a[4 * g + 1] * inv + bv.y;
      tot[4 * g + 2] += a[4 * g + 2] * inv + bv.z;
      tot[4 * g + 3] += a[4 * g + 3] * inv + bv.w;
    }
  }
  // residual added R times (once per relation in the reference)
  {
    const float4* rv4 = (const float4*)(hf + (size_t)node * FDIM + hd * DIM);
#pragma unroll
    for (int g = 0; g < 8; ++g) {
      float4 rv = rv4[g];
      tot[4 * g]     += R * rv.x;
      tot[4 * g + 1] += R * rv.y;
      tot[4 * g + 2] += R * rv.z;
      tot[4 * g + 3] += R * rv.w;
    }
  }
  // head-mean: butterfly over the 4 head lanes; all lanes end with full sums
#pragma unroll
  for (int i = 0; i < 32; ++i) {
    float v = tot[i];
    v += __shfl_xor(v, 1);
    v += __shfl_xor(v, 2);
    tot[i] = v * 0.25f;
  }
  if (sub == 0) {   // lane hd stores dims [hd*8, hd*8+8): quad writes 128B contiguous
    float4* op = (float4*)(out + (size_t)node * 32 + hd * 8);
    op[0] = make_float4(tot[hd * 8], tot[hd * 8 + 1], tot[hd * 8 + 2], tot[hd * 8 + 3]);
    op[1] = make_float4(tot[hd * 8 + 4], tot[hd * 8 + 5], tot[hd * 8 + 6], tot[hd * 8 + 7]);
  }
}

extern "C" void kernel_launch(void* const* d_in, const int* in_sizes, int n_in,
                              void* d_out, int out_size, void* d_ws, size_t ws_size,
                              hipStream_t stream) {
  const float* x   = (const float*)d_in[0];
  const float* W1  = (const float*)d_in[1];
  const float* al1 = (const float*)d_in[2];
  const float* ar1 = (const float*)d_in[3];
  const float* b1  = (const float*)d_in[4];
  const float* W2  = (const float*)d_in[5];
  const float* al2 = (const float*)d_in[6];
  const float* ar2 = (const float*)d_in[7];
  const float* b2  = (const float*)d_in[8];
  const int* edges = (const int*)d_in[9];
  float* out = (float*)d_out;

  const int N = in_sizes[0] / FDIM;          // 50000
  const int R = in_sizes[1] / (FDIM * FDIM); // 2
  const int E = in_sizes[9] / (2 * R);       // 800000

  char* ws = (char*)d_ws;
  size_t off = 0;
  auto alloc = [&](size_t bytes) {
    char* p = ws + off;
    off += (bytes + 255) & ~(size_t)255;
    return p;
  };
  unsigned short* featb = (unsigned short*)alloc((size_t)R * N * FDIM * 2);  // 25.6 MB
  unsigned short* WT    = (unsigned short*)alloc((size_t)2 * R * FDIM * FDIM * 2);
  float* el = (float*)alloc((size_t)R * N * 4 * 4);
  float* er = (float*)alloc((size_t)R * N * 4 * 4);
  float* h  = (float*)alloc((size_t)N * FDIM * 4);
  int* head2 = (int*)alloc((size_t)R * N * 2 * 4);
  int2* nxt2 = (int2*)alloc((size_t)R * E * 8);

  hipMemsetAsync(head2, 0xFF, (size_t)R * N * 2 * 4, stream);

  int NW = 2 * R * FDIM * FDIM;
  prep_kernel<<<(NW + R * E + 255) / 256, 256, 0, stream>>>(
      W1, W2, WT, edges, head2, nxt2, E, N, R);

  dim3 mmgrid((N + 63) / 64, R);
  dim3 cgrid((N * HEADS + 255) / 256, R);
  int agrid = (N * 8 + 255) / 256;

  // ---- layer 1 ----
  mm_kernel<<<mmgrid, 256, 0, stream>>>(x, WT, featb, N);
  coef_kernel<<<cgrid, 256, 0, stream>>>(featb, al1, ar1, el, er, N);
  agg1_kernel<<<agrid, 256, 0, stream>>>(featb, el, er, head2, nxt2, b1, h, N, E, R);

  // ---- layer 2 ----
  mm_kernel<<<mmgrid, 256, 0, stream>>>(h, WT + (size_t)R * FDIM * FDIM, featb, N);
  coef_kernel<<<cgrid, 256, 0, stream>>>(featb, al2, ar2, el, er, N);
  agg2_kernel<<<agrid, 256, 0, stream>>>(featb, el, er, head2, nxt2, b2, h, out, N, E, R);
}